// Round 1
// baseline (55.468 us; speedup 1.0000x reference)
//
#include <hip/hip_runtime.h>
#include <hip/hip_bf16.h>

// Shift3x3: out[b,c,i,j] = x[b,c, i+di(c%5), j+dj(c%5)], zero at borders.
//   c%5==0: (di,dj)=(-1, 0)  (read row above)
//   c%5==1: (di,dj)=( 0,-1)  (read col left)
//   c%5==2: (di,dj)=( 0, 0)  (identity)
//   c%5==3: (di,dj)=( 0,+1)  (read col right)
//   c%5==4: (di,dj)=(+1, 0)  (read row below)
// Shapes: B=32, C=384, H=56, W=56, float32 in/out. Pure memory-bound.

#define SH_W 56
#define SH_H 56
#define SH_C 384
#define SH_W4 14            // W/4 float4 per row
#define SH_PLANE4 784       // H * W4
#define SH_PLANE 3136       // H * W

__global__ void Shift3x3_kernel(const float* __restrict__ x,
                                float* __restrict__ out, int n4) {
    int idx = blockIdx.x * blockDim.x + threadIdx.x;
    const int stride = gridDim.x * blockDim.x;
    for (; idx < n4; idx += stride) {
        int plane = idx / SH_PLANE4;          // b*C + c
        int rem   = idx - plane * SH_PLANE4;  // within plane, float4 units
        int i     = rem / SH_W4;              // row
        int j4    = rem - i * SH_W4;          // float4 col
        int c     = plane % SH_C;
        int mod   = c % 5;
        int j     = j4 * 4;
        int base  = plane * SH_PLANE + i * SH_W + j;

        float4 v;
        if (mod == 2) {
            v = *reinterpret_cast<const float4*>(x + base);
        } else if (mod == 0) {
            v = (i == 0) ? make_float4(0.f, 0.f, 0.f, 0.f)
                         : *reinterpret_cast<const float4*>(x + base - SH_W);
        } else if (mod == 4) {
            v = (i == SH_H - 1) ? make_float4(0.f, 0.f, 0.f, 0.f)
                                : *reinterpret_cast<const float4*>(x + base + SH_W);
        } else if (mod == 1) {
            const float* p = x + base;
            v.x = (j == 0) ? 0.f : p[-1];
            v.y = p[0];
            v.z = p[1];
            v.w = p[2];
        } else {  // mod == 3
            const float* p = x + base;
            v.x = p[1];
            v.y = p[2];
            v.z = p[3];
            v.w = (j == SH_W - 4) ? 0.f : p[4];
        }
        *reinterpret_cast<float4*>(out + base) = v;
    }
}

extern "C" void kernel_launch(void* const* d_in, const int* in_sizes, int n_in,
                              void* d_out, int out_size, void* d_ws, size_t ws_size,
                              hipStream_t stream) {
    const float* x = (const float*)d_in[0];
    float* out = (float*)d_out;
    int n4 = out_size / 4;  // 9,633,792 float4 stores
    int block = 256;
    int grid = (n4 + block - 1) / block;
    if (grid > 2048) grid = 2048;
    Shift3x3_kernel<<<grid, block, 0, stream>>>(x, out, n4);
}